// Round 1
// 261.519 us; speedup vs baseline: 1.0955x; 1.0955x over previous
//
#include <hip/hip_runtime.h>

#define LOG2E 1.4426950408889634f

constexpr int Dn = 128;
constexpr int Nn = 16384;
constexpr int Kn = 64;
constexpr int Bn = 16;

typedef __attribute__((ext_vector_type(16))) float f32x16;

// Prep: folds mu-normalize, exp(-log_sigma), factor -2, k-constant and log2e.
// NEW layout for scalar loads in main: wout[((k>>3)*64 + dh)*8 + (k&7)] so the
// 8-k slice of wave g at a given dh is 128 contiguous bytes (2x s_load_dwordx16).
__global__ __launch_bounds__(64) void gmm_prep(const float* __restrict__ mu,
                                               const float* __restrict__ log_sigma,
                                               const float* __restrict__ log_alpha,
                                               float4* __restrict__ wout,
                                               float* __restrict__ cout) {
    const int k = blockIdx.x;
    const int l = threadIdx.x;        // l == dh
    const int d0 = 2 * l;
    float m0 = mu[k * Dn + d0];
    float m1 = mu[k * Dn + d0 + 1];
    float s0 = log_sigma[k * Dn + d0];
    float s1 = log_sigma[k * Dn + d0 + 1];
    float nrm2 = m0 * m0 + m1 * m1;
    float lss = s0 + s1;
    #pragma unroll
    for (int off = 32; off > 0; off >>= 1) {
        nrm2 += __shfl_xor(nrm2, off);
        lss  += __shfl_xor(lss, off);
    }
    const float inv_nrm = 1.0f / fmaxf(sqrtf(nrm2), 1e-12f);
    const float mn0 = m0 * inv_nrm, mn1 = m1 * inv_nrm;
    const float si0 = expf(-s0), si1 = expf(-s1);
    float mt = mn0 * mn0 * si0 + mn1 * mn1 * si1;
    #pragma unroll
    for (int off = 32; off > 0; off >>= 1) mt += __shfl_xor(mt, off);
    wout[((k >> 3) * 64 + l) * 8 + (k & 7)] =
        make_float4(-si0 * LOG2E, 2.0f * mn0 * si0 * LOG2E,
                    -si1 * LOG2E, 2.0f * mn1 * si1 * LOG2E);
    if (l == 0) cout[k] = (log_alpha[k] - 0.5f * lss - mt) * LOG2E;
}

__device__ __forceinline__ float4 fmax4(float4 a, float4 b) {
    return make_float4(fmaxf(a.x, b.x), fmaxf(a.y, b.y),
                       fmaxf(a.z, b.z), fmaxf(a.w, b.w));
}
__device__ __forceinline__ float4 add4(float4 a, float4 b) {
    return make_float4(a.x + b.x, a.y + b.y, a.z + b.z, a.w + b.w);
}

// Main v2: 512 threads = 8 waves, 256-n window (1024 blocks = 4 blocks/CU).
// Wave g owns k in [8g,8g+8); lane owns 4 consecutive n's -> acc[8][4] = 32
// VGPRs, live set ~56 -> fits the 64-VGPR / 8-waves-per-EU budget with NO
// AGPR shuffling and NO scratch (round-0 showed VGPR=64 + 13MB scratch).
// W is wave-uniform -> held in SGPRs via s_load_dwordx16 (inline asm so it
// cannot fall back to VGPRs). t = x*x is shared across the 8 k's so every
// FMA has exactly one SGPR operand (HW limit: 1 SGPR read per VALU instr).
// Main loop has zero LDS traffic; LDS = 8KB softmax buffer only.
__global__ __launch_bounds__(512)
void gmm_main(const float* __restrict__ x,
              const float4* __restrict__ w,
              const float* __restrict__ cks,
              float* __restrict__ out) {
    __shared__ float sRed[8][256];     // cross-wave softmax buffer

    const int tid = threadIdx.x;
    const int g = __builtin_amdgcn_readfirstlane(tid >> 6);  // wave id, uniform
    const int l = tid & 63;
    const int b = blockIdx.y;
    const int nloc = 4 * l;                       // lane's n offset in window
    const size_t nbase = (size_t)blockIdx.x * 256 + nloc;

    // init acc with the per-k constant (folds the epilogue add); uniform loads
    float acc[8][4];
    #pragma unroll
    for (int k = 0; k < 8; ++k) {
        const float c = cks[g * 8 + k];
        #pragma unroll
        for (int j = 0; j < 4; ++j) acc[k][j] = c;
    }

    const float* xp = x + (size_t)b * Dn * Nn + nbase;
    const char* wp = (const char*)w + (size_t)g * 8192;   // g-slice: 64dh*8k*16B

    #pragma unroll 1
    for (int dh = 0; dh < Dn / 2; ++dh) {
        const float4 xa = *(const float4*)(xp);        // d=2dh,   n..n+3
        const float4 xb = *(const float4*)(xp + Nn);   // d=2dh+1, n..n+3
        xp += 2 * Nn;

        // 32 floats of W for (g, dh) into SGPRs: 8k x {wx0,wy0,wx1,wy1}
        f32x16 w0, w1;
        asm("s_load_dwordx16 %0, %2, 0x0\n\t"
            "s_load_dwordx16 %1, %2, 0x40\n\t"
            "s_waitcnt lgkmcnt(0)"
            : "=&s"(w0), "=&s"(w1)
            : "s"(wp));
        wp += 128;

        const float4 ta = make_float4(xa.x * xa.x, xa.y * xa.y,
                                      xa.z * xa.z, xa.w * xa.w);
        const float4 tb = make_float4(xb.x * xb.x, xb.y * xb.y,
                                      xb.z * xb.z, xb.w * xb.w);

#define GMM_K(WV, KK, A)                                                  \
        {                                                                 \
            const float wx0 = WV[4 * KK + 0], wy0 = WV[4 * KK + 1];       \
            const float wx1 = WV[4 * KK + 2], wy1 = WV[4 * KK + 3];       \
            A[0] = fmaf(wx0, ta.x, A[0]); A[0] = fmaf(wy0, xa.x, A[0]);   \
            A[0] = fmaf(wx1, tb.x, A[0]); A[0] = fmaf(wy1, xb.x, A[0]);   \
            A[1] = fmaf(wx0, ta.y, A[1]); A[1] = fmaf(wy0, xa.y, A[1]);   \
            A[1] = fmaf(wx1, tb.y, A[1]); A[1] = fmaf(wy1, xb.y, A[1]);   \
            A[2] = fmaf(wx0, ta.z, A[2]); A[2] = fmaf(wy0, xa.z, A[2]);   \
            A[2] = fmaf(wx1, tb.z, A[2]); A[2] = fmaf(wy1, xb.z, A[2]);   \
            A[3] = fmaf(wx0, ta.w, A[3]); A[3] = fmaf(wy0, xa.w, A[3]);   \
            A[3] = fmaf(wx1, tb.w, A[3]); A[3] = fmaf(wy1, xb.w, A[3]);   \
        }

        GMM_K(w0, 0, acc[0]); GMM_K(w0, 1, acc[1]);
        GMM_K(w0, 2, acc[2]); GMM_K(w0, 3, acc[3]);
        GMM_K(w1, 0, acc[4]); GMM_K(w1, 1, acc[5]);
        GMM_K(w1, 2, acc[6]); GMM_K(w1, 3, acc[7]);
#undef GMM_K
    }

    // ---- softmax: cross-wave max over all 64 k ----
    float4 m = make_float4(acc[0][0], acc[0][1], acc[0][2], acc[0][3]);
    #pragma unroll
    for (int k = 1; k < 8; ++k)
        m = fmax4(m, make_float4(acc[k][0], acc[k][1], acc[k][2], acc[k][3]));
    *(float4*)&sRed[g][nloc] = m;
    __syncthreads();
    #pragma unroll
    for (int gg = 0; gg < 8; ++gg)
        m = fmax4(m, *(const float4*)&sRed[gg][nloc]);
    __syncthreads();   // before reusing sRed for sums

    // ---- exp2 + cross-wave sum ----
    float4 s = make_float4(0.f, 0.f, 0.f, 0.f);
    #pragma unroll
    for (int k = 0; k < 8; ++k) {
        acc[k][0] = __builtin_amdgcn_exp2f(acc[k][0] - m.x); s.x += acc[k][0];
        acc[k][1] = __builtin_amdgcn_exp2f(acc[k][1] - m.y); s.y += acc[k][1];
        acc[k][2] = __builtin_amdgcn_exp2f(acc[k][2] - m.z); s.z += acc[k][2];
        acc[k][3] = __builtin_amdgcn_exp2f(acc[k][3] - m.w); s.w += acc[k][3];
    }
    *(float4*)&sRed[g][nloc] = s;
    __syncthreads();
    s = make_float4(0.f, 0.f, 0.f, 0.f);
    #pragma unroll
    for (int gg = 0; gg < 8; ++gg)
        s = add4(s, *(const float4*)&sRed[gg][nloc]);
    const float4 r = make_float4(1.0f / s.x, 1.0f / s.y, 1.0f / s.z, 1.0f / s.w);

    // ---- store: out[b][k][n], one float4 per k, coalesced ----
    float* op = out + (size_t)(b * Kn + g * 8) * Nn + nbase;
    #pragma unroll
    for (int k = 0; k < 8; ++k) {
        *(float4*)op = make_float4(acc[k][0] * r.x, acc[k][1] * r.y,
                                   acc[k][2] * r.z, acc[k][3] * r.w);
        op += Nn;
    }
}

extern "C" void kernel_launch(void* const* d_in, const int* in_sizes, int n_in,
                              void* d_out, int out_size, void* d_ws, size_t ws_size,
                              hipStream_t stream) {
    const float* x  = (const float*)d_in[0];
    const float* mu = (const float*)d_in[1];
    const float* ls = (const float*)d_in[2];
    const float* la = (const float*)d_in[3];
    float* out = (float*)d_out;

    float4* wbuf = (float4*)d_ws;
    float*  cbuf = (float*)((char*)d_ws + (size_t)Kn * (Dn / 2) * sizeof(float4));

    gmm_prep<<<dim3(Kn), dim3(64), 0, stream>>>(mu, ls, la, wbuf, cbuf);
    gmm_main<<<dim3(Nn / 256, Bn), dim3(512), 0, stream>>>(x, wbuf, cbuf, out);
}